// Round 8
// baseline (301.859 us; speedup 1.0000x reference)
//
#include <hip/hip_runtime.h>
#include <cmath>

#define B_   128
#define H_   256
#define W_   256
#define WC_  129
#define L_   182
#define NGRP 4
#define SPAD 258      // float stride per spectrum column (even -> float2 stores)
#define PI_F 3.14159265358979f

// ---------------------------------------------------------------------------
// Two interleaved wave-synchronous 256-point DIF FFTs across one 64-lane wave.
// FFT A in slots 0..3, FFT B in slots 4..7; slot j holds x[l + 64*(j&3)].
// Twiddles shared (half the sincos); two independent shfl chains for ILP.
// Output: storage q = l + 64*(j&3) holds X[bitrev8(q)] of the respective FFT.
// ---------------------------------------------------------------------------
__device__ __forceinline__ void fft256x2_wave(float vr[8], float vi[8], int l) {
  float c0, s0;
  __sincosf(-2.f * PI_F * (float)l / 256.f, &s0, &c0);  // W256^l
  float c1 = s0, s1 = -c0;                              // W256^(l+64)
  float c2 = c0 * c0 - s0 * s0, s2 = 2.f * c0 * s0;     // W128^l
  #pragma unroll
  for (int f = 0; f < 8; f += 4) {
    float ur = vr[f+0] + vr[f+2], ui = vi[f+0] + vi[f+2];
    float dr = vr[f+0] - vr[f+2], di = vi[f+0] - vi[f+2];
    vr[f+0] = ur; vi[f+0] = ui;
    vr[f+2] = dr * c0 - di * s0; vi[f+2] = dr * s0 + di * c0;
    ur = vr[f+1] + vr[f+3]; ui = vi[f+1] + vi[f+3];
    dr = vr[f+1] - vr[f+3]; di = vi[f+1] - vi[f+3];
    vr[f+1] = ur; vi[f+1] = ui;
    vr[f+3] = dr * c1 - di * s1; vi[f+3] = dr * s1 + di * c1;
    ur = vr[f+0] + vr[f+1]; ui = vi[f+0] + vi[f+1];
    dr = vr[f+0] - vr[f+1]; di = vi[f+0] - vi[f+1];
    vr[f+0] = ur; vi[f+0] = ui;
    vr[f+1] = dr * c2 - di * s2; vi[f+1] = dr * s2 + di * c2;
    ur = vr[f+2] + vr[f+3]; ui = vi[f+2] + vi[f+3];
    dr = vr[f+2] - vr[f+3]; di = vi[f+2] - vi[f+3];
    vr[f+2] = ur; vi[f+2] = ui;
    vr[f+3] = dr * c2 - di * s2; vi[f+3] = dr * s2 + di * c2;
  }
  #pragma unroll
  for (int h = 32; h >= 1; h >>= 1) {
    int i = l & (h - 1);
    float c, s;
    __sincosf(-PI_F * (float)i / (float)h, &s, &c);
    bool up = (l & h) != 0;
    float cc = up ? c : 1.f;
    float ss = up ? s : 0.f;
    float sgn = up ? -1.f : 1.f;
    #pragma unroll
    for (int j = 0; j < 8; ++j) {
      float br = __shfl_xor(vr[j], h, 64);
      float bi = __shfl_xor(vi[j], h, 64);
      float tr = fmaf(sgn, vr[j], br);
      float ti = fmaf(sgn, vi[j], bi);
      vr[j] = tr * cc - ti * ss;
      vi[j] = tr * ss + ti * cc;
    }
  }
}

// ---------------------------------------------------------------------------
// Fused rows+cols kernel, 4 blocks per image (512 blocks = 2/CU, 32 waves/CU).
// Each block row-FFTs all 256 rows (packed: two real rows per complex FFT,
// conjugate-unpacked IN REGISTERS via the bitrev-palindrome partner permute:
// q in [2^j,2^{j+1}) partners 3*2^j-1-q -> slot0 bpermute, slot1 xor63,
// slot2<->slot3 xor63), keeps its 33 (or 32) spectrum columns in LDS
// (~68 KB -> 2 blocks/CU), col-FFTs, log-power-bins, stores partial[b][c][L].
// XCD-grouped mapping: all 4 sibling blocks of image b land on XCD b&7, so
// the duplicate image reads are L2-local (r7: FETCH stayed ~1x input).
// Spectrum compaction: kept kx = bitrev8(q)<=128 <=> q even (s=q>>1) or q==1
// (s=128). spec[s][y] stride 258: row-phase float2 stores at (sl*258+2p)
// (banks 2*sl mod 32 -> 2-way, free); col-phase reads stride-1 in y.
// ---------------------------------------------------------------------------
__global__ __launch_bounds__(1024, 8) void mega_kernel(
    const float* __restrict__ data, const int* __restrict__ radius,
    float* __restrict__ partial, float* __restrict__ cntpart) {
  __shared__ float specR[33 * SPAD];   // 34,056 B
  __shared__ float specI[33 * SPAD];   // 34,056 B
  __shared__ float lbins[L_];
  __shared__ float lcnt[L_];
  int tid = threadIdx.x;
  int w = tid >> 6, l = tid & 63;
  int rr = blockIdx.x >> 3;
  int b = (blockIdx.x & 7) + 8 * (rr >> 2);   // image
  int c = rr & 3;                             // column group
  int s0 = c ? (32 * c + 1) : 0;              // {0,33,65,97}
  int ns = c ? 32 : 33;
  bool do_cnt = (b == 0);
  for (int i = tid; i < L_; i += 1024) { lbins[i] = 0.f; lcnt[i] = 0.f; }
  const float* base = data + (size_t)b * 3 * (H_ * W_);
  // slot0 conjugate-partner lane: p0 = 3*msb(l)-1-l (0->0, 1->1).
  int p0 = l ? (3 * (1 << (31 - __clz(l))) - 1 - l) : 0;

  // ---- Row phase: 4 rounds x 16 waves x 2 packed FFTs = 128 pairs ---------
  for (int t = 0; t < 4; ++t) {
    int pA = t * 32 + w;       // rows 2pA, 2pA+1 in FFT-A
    int pB = pA + 16;          // rows 2pB, 2pB+1 in FFT-B
    float vr[8], vi[8];
    #pragma unroll
    for (int j = 0; j < 4; ++j) {
      int xx = l + 64 * j;
      const float* q0 = base + (size_t)(2 * pA) * W_ + xx;
      vr[j]     = fmaf(0.299f, q0[0],  fmaf(0.587f, q0[H_*W_],     0.114f * q0[2*H_*W_]));
      vi[j]     = fmaf(0.299f, q0[W_], fmaf(0.587f, q0[H_*W_+W_],  0.114f * q0[2*H_*W_+W_]));
      const float* q1 = base + (size_t)(2 * pB) * W_ + xx;
      vr[4 + j] = fmaf(0.299f, q1[0],  fmaf(0.587f, q1[H_*W_],     0.114f * q1[2*H_*W_]));
      vi[4 + j] = fmaf(0.299f, q1[W_], fmaf(0.587f, q1[H_*W_+W_],  0.114f * q1[2*H_*W_+W_]));
    }
    fft256x2_wave(vr, vi, l);
    #pragma unroll
    for (int f = 0; f < 8; f += 4) {
      int pp = (f == 0) ? pA : pB;
      float znr[4], zni[4];
      znr[0] = __shfl(vr[f + 0], p0, 64);     zni[0] = __shfl(vi[f + 0], p0, 64);
      znr[1] = __shfl_xor(vr[f + 1], 63, 64); zni[1] = __shfl_xor(vi[f + 1], 63, 64);
      znr[2] = __shfl_xor(vr[f + 3], 63, 64); zni[2] = __shfl_xor(vi[f + 3], 63, 64);
      znr[3] = __shfl_xor(vr[f + 2], 63, 64); zni[3] = __shfl_xor(vi[f + 2], 63, 64);
      #pragma unroll
      for (int j = 0; j < 4; ++j) {
        int q = l + 64 * j;
        int s = (q & 1) ? ((q == 1) ? 128 : -1) : (q >> 1);
        int sl = s - s0;
        if (s >= 0 && sl >= 0 && sl < ns) {
          float2 R, I;
          R.x = 0.5f * (vr[f + j] + znr[j]);   // A.re (even row)
          I.x = 0.5f * (vi[f + j] - zni[j]);   // A.im
          R.y = 0.5f * (vi[f + j] + zni[j]);   // B.re (odd row)
          I.y = 0.5f * (znr[j] - vr[f + j]);   // B.im
          *(float2*)&specR[sl * SPAD + 2 * pp] = R;
          *(float2*)&specI[sl * SPAD + 2 * pp] = I;
        }
      }
    }
  }
  __syncthreads();

  // ---- Col phase: <=2 rounds x 16 waves x 2 cols ---------------------------
  for (int t = 0; t < 2; ++t) {
    if (t * 32 >= ns) break;
    int sA = t * 32 + w, sB = sA + 16;
    bool vA = sA < ns, vB = sB < ns;
    int eA = vA ? sA : 0, eB = vB ? sB : 0;
    float vr[8], vi[8];
    #pragma unroll
    for (int j = 0; j < 4; ++j) {
      int y = l + 64 * j;
      vr[j]     = specR[eA * SPAD + y];
      vi[j]     = specI[eA * SPAD + y];
      vr[4 + j] = specR[eB * SPAD + y];
      vi[4 + j] = specI[eB * SPAD + y];
    }
    fft256x2_wave(vr, vi, l);
    int sgA = s0 + eA, sgB = s0 + eB;
    int kxA = (sgA == 128) ? 128 : (int)(__brev((unsigned)(2 * sgA)) >> 24);
    int kxB = (sgB == 128) ? 128 : (int)(__brev((unsigned)(2 * sgB)) >> 24);
    int rb = 4 * (int)(__brev((unsigned)l) >> 26);
    #pragma unroll
    for (int j = 0; j < 4; ++j) {
      int ky = rb + ((j == 1) ? 2 : (j == 2) ? 1 : j);  // bitrev8(l+64j)
      if (vA) {
        int bin = radius[ky * WC_ + kxA];
        float pw = vr[j] * vr[j] + vi[j] * vi[j];
        atomicAdd(&lbins[bin], 20.f * __logf(pw + 1e-8f));
        if (do_cnt) atomicAdd(&lcnt[bin], 1.f);
      }
      if (vB) {
        int bin = radius[ky * WC_ + kxB];
        float pw = vr[4 + j] * vr[4 + j] + vi[4 + j] * vi[4 + j];
        atomicAdd(&lbins[bin], 20.f * __logf(pw + 1e-8f));
        if (do_cnt) atomicAdd(&lcnt[bin], 1.f);
      }
    }
  }
  __syncthreads();
  float* pp = partial + ((size_t)b * NGRP + c) * L_;
  for (int i = tid; i < L_; i += 1024) pp[i] = lbins[i];
  if (do_cnt)
    for (int i = tid; i < L_; i += 1024) cntpart[c * L_ + i] = lcnt[i];
}

// One wave per batch sample: reduce 4 value+count partials, segment mean,
// min-max normalize, L1 vs mean — in-register via shfl (r2-validated math).
__global__ __launch_bounds__(64) void loss_kernel(
    const float* __restrict__ partial, const float* __restrict__ cntpart,
    const float* __restrict__ mean, float* __restrict__ lpart) {
  int b = blockIdx.x;
  int l = threadIdx.x;
  const float* pb = partial + (size_t)b * NGRP * L_;
  float s0 = 0.f, s1 = 0.f, s2 = 0.f;
  float n0 = 0.f, n1 = 0.f, n2 = 0.f;
  bool has2 = (l + 128) < L_;
  #pragma unroll
  for (int g = 0; g < NGRP; ++g) {
    s0 += pb[g * L_ + l];        n0 += cntpart[g * L_ + l];
    s1 += pb[g * L_ + l + 64];   n1 += cntpart[g * L_ + l + 64];
    if (has2) { s2 += pb[g * L_ + l + 128]; n2 += cntpart[g * L_ + l + 128]; }
  }
  float pa = s0 / n0;
  float pc = s1 / n1;
  float pe = has2 ? (s2 / n2) : 0.f;
  float mn = fminf(pa, pc);
  if (has2) mn = fminf(mn, pe);
  #pragma unroll
  for (int h = 32; h >= 1; h >>= 1) mn = fminf(mn, __shfl_xor(mn, h, 64));
  float mxr = fmaxf(pa, pc);
  if (has2) mxr = fmaxf(mxr, pe);
  #pragma unroll
  for (int h = 32; h >= 1; h >>= 1) mxr = fmaxf(mxr, __shfl_xor(mxr, h, 64));
  float mx = mxr - mn;  // max(profile - mn): max attained at the same element
  float s = fabsf((pa - mn) / mx - mean[l]) +
            fabsf((pc - mn) / mx - mean[l + 64]);
  if (has2) s += fabsf((pe - mn) / mx - mean[l + 128]);
  #pragma unroll
  for (int h = 32; h >= 1; h >>= 1) s += __shfl_xor(s, h, 64);
  if (l == 0) lpart[b] = s;
}

// Final: one wave sums the 128 per-sample losses, plain store to out.
__global__ __launch_bounds__(64) void final_kernel(
    const float* __restrict__ lpart, float* __restrict__ out) {
  int l = threadIdx.x;
  float v = lpart[l] + lpart[l + 64];
  #pragma unroll
  for (int h = 32; h >= 1; h >>= 1) v += __shfl_xor(v, h, 64);
  if (l == 0) out[0] = v;
}

extern "C" void kernel_launch(void* const* d_in, const int* in_sizes, int n_in,
                              void* d_out, int out_size, void* d_ws, size_t ws_size,
                              hipStream_t stream) {
  const float* data   = (const float*)d_in[0];  // [128,3,256,256] f32
  const float* mean   = (const float*)d_in[1];  // [182] f32
  const int*   radius = (const int*)d_in[2];    // [256,129] i32
  float* out = (float*)d_out;                   // scalar f32

  float* partial = (float*)d_ws;                   // [B][4][L]
  float* cntpart = partial + (size_t)B_ * NGRP * L_;  // [4][L]
  float* lpart   = cntpart + (size_t)NGRP * L_;    // [B]

  mega_kernel<<<B_ * NGRP, 1024, 0, stream>>>(data, radius, partial, cntpart);
  loss_kernel<<<B_, 64, 0, stream>>>(partial, cntpart, mean, lpart);
  final_kernel<<<1, 64, 0, stream>>>(lpart, out);
}